// Round 2
// baseline (111.427 us; speedup 1.0000x reference)
//
#include <hip/hip_runtime.h>
#include <hip/hip_bf16.h>

// ColumnConsistencyLoss: B=16, T=8192, C=128.
// out = mean over columns c with n_c>1 of (q_c - t_c/n_c)/(n_c*C)
//   n_c = # valid rows with seg=c ; q_c = sum z2/z^2 over those rows
//   s[c][j] = sum p_j over those rows ; t_c = sum_j s[c][j]^2
//
// Round-10: producer/consumer pipelined fused kernel.
//  - 4 chunks x 8 ksteps (128 rows each), triple-buffered 32 KiB P-chunks.
//    Prologue: all 16 waves produce chunks 0,1 (one kstep each).
//    Loop c=0..3: waves 8-15 GEMM chunk c (2 MFMAs/kstep per wave, (m,nh)
//    split) while waves 0-7 produce chunk c+2. The old 2.2-2.5 us LDS-bound
//    GEMM tail (12 idle waves) now hides under phase-1 HBM wait.
//  - 32-lane reduce via 4x DPP row_ror adds + 1 ds_swizzle (was 5x ds
//    shuffles x2 values): LDS-pipe ops per block 2560 -> 512, freeing the
//    pipe for the concurrent GEMM ds_read_b128 stream.
//  Global traffic, MFMA count, fragment layouts (verified: absmax 0.0
//  rounds 7-9) unchanged.
// ~85-90 us of dur_us is harness ws-poison (268 MB fill @ 6.5 TB/s) +
// d_in restore — not addressable from kernel code.

#define NROWS 131072
#define CC    128
#define NB    256
#define RPB   512   // rows per block
#define BUF_USHORTS (8 * 4 * 64 * 8)  // 8 ksteps x 4 nt x 64 lanes x 8 bf16

typedef float f32x16 __attribute__((ext_vector_type(16)));
typedef short bf16x8 __attribute__((ext_vector_type(8)));

union U4V { uint4 u; bf16x8 v; };
union H2U { __hip_bfloat162 h; unsigned int u; };

// Sum over 32 consecutive lanes: 4x DPP row_ror (VALU pipe, rows of 16)
// + 1 ds_swizzle xor16 to combine the two 16-rows. All lanes get the sum.
__device__ __forceinline__ float red32(float x) {
  x += __int_as_float(__builtin_amdgcn_update_dpp(
      0, __float_as_int(x), 0x121, 0xF, 0xF, true));  // row_ror:1
  x += __int_as_float(__builtin_amdgcn_update_dpp(
      0, __float_as_int(x), 0x122, 0xF, 0xF, true));  // row_ror:2
  x += __int_as_float(__builtin_amdgcn_update_dpp(
      0, __float_as_int(x), 0x124, 0xF, 0xF, true));  // row_ror:4
  x += __int_as_float(__builtin_amdgcn_update_dpp(
      0, __float_as_int(x), 0x128, 0xF, 0xF, true));  // row_ror:8
  x += __int_as_float(
      __builtin_amdgcn_ds_swizzle(__float_as_int(x), 0x401F));  // xor 16
  return x;
}

__device__ __forceinline__ void load_x(const float* __restrict__ logits,
                                       int b, int rb, int j5,
                                       float (&x)[8][4]) {
#pragma unroll
  for (int i = 0; i < 8; ++i) {
    const float* rp = logits + (size_t)(b * RPB + rb + i) * CC + j5;
#pragma unroll
    for (int nt = 0; nt < 4; ++nt) x[i][nt] = rp[nt * 32];
  }
}

// exp -> row softmax stats -> bf16 pack to chunk buf (MFMA B-frag order,
// layout identical to rounds 7-9) -> n/q LDS atomics.
__device__ __forceinline__ void finish_ts(float (&x)[8][4], const int* sm,
                                          float* n_lds, float* q_lds,
                                          ushort* buf, int tsl, int rb,
                                          int lane, int j5) {
  float inv[8], qr[8];
#pragma unroll
  for (int i = 0; i < 8; ++i) {
    float z = 0.f, z2 = 0.f;
#pragma unroll
    for (int nt = 0; nt < 4; ++nt) {
      const float e = __expf(x[i][nt]);
      x[i][nt] = e; z += e; z2 += e * e;
    }
    z = red32(z);
    z2 = red32(z2);
    inv[i] = 1.0f / z;
    qr[i] = z2 * inv[i] * inv[i];
  }
#pragma unroll
  for (int nt = 0; nt < 4; ++nt) {
    unsigned int d[4];
#pragma unroll
    for (int k = 0; k < 4; ++k) {
      H2U h;
      h.h = __float22bfloat162_rn(make_float2(
          x[2 * k][nt] * inv[2 * k], x[2 * k + 1][nt] * inv[2 * k + 1]));
      d[k] = h.u;
    }
    *(uint4*)(buf + ((size_t)(tsl * 4 + nt) * 64 + lane) * 8) =
        make_uint4(d[0], d[1], d[2], d[3]);
  }
  if (j5 == 0) {
#pragma unroll
    for (int i = 0; i < 8; ++i) {
      const int smv = sm[rb + i];
      if (smv >> 16) {
        atomicAdd(&n_lds[smv & 0xFFFF], 1.0f);
        atomicAdd(&q_lds[smv & 0xFFFF], qr[i]);
      }
    }
  }
}

// ---------------- Fused: pipelined softmax-produce / one-hot-MFMA consume --
// 256 blocks x 1024 thr (16 waves). LDS ~99.5 KiB -> 1 block/CU (grid=256).
__global__ __launch_bounds__(1024) void fused_kernel(
    const float* __restrict__ logits, const int* __restrict__ seg,
    const int* __restrict__ mask, float* __restrict__ slab_s,
    float* __restrict__ slab_n, float* __restrict__ slab_q,
    float* __restrict__ acc) {
  __shared__ ushort Pbuf[3][BUF_USHORTS];  // 96 KiB, chunk k -> Pbuf[k%3]
  __shared__ int sm[RPB];                  // 2 KiB: seg | mask<<16
  __shared__ unsigned int sg4[128];        // packed seg-bytes (255=invalid)
  __shared__ float n_lds[CC], q_lds[CC];
  const int t = threadIdx.x, b = blockIdx.x;
  const int wave = t >> 6, lane = t & 63;
  const int q = lane >> 5, j5 = lane & 31;

  // Prologue: every wave produces kstep ts=wave (chunks 0,1). Loads issued
  // before B0 so they overlap the sm staging + barrier latency.
  float x[8][4];
  load_x(logits, b, wave * 16 + q * 8, j5, x);

  if (b == 0 && t < 4) ((unsigned int*)acc)[t] = 0u;  // (total,count,ticket)
  if (t < RPB) sm[t] = seg[b * RPB + t] | (mask[b * RPB + t] << 16);
  if (t < CC) { n_lds[t] = 0.f; q_lds[t] = 0.f; }
  __syncthreads();  // B0: sm visible, n/q zeroed
  if (t < 128) {
    unsigned int w = 0;
#pragma unroll
    for (int k = 0; k < 4; ++k) {
      const int smv = sm[t * 4 + k];
      const unsigned int sv = (smv >> 16) ? (unsigned int)(smv & 0xFFFF) : 255u;
      w |= sv << (8 * k);
    }
    sg4[t] = w;
  }
  finish_ts(x, sm, n_lds, q_lds, Pbuf[wave >> 3], wave & 7,
            wave * 16 + q * 8, lane, j5);
  __syncthreads();  // B1: chunks 0,1 + sg4 ready

  // Consumer geometry: wave 8+i -> m-tile i&3, n-halftile i>>2.
  const int ci = wave - 8;
  const int m = ci & 3, nh = ci >> 2;
  const int mm = m * 32 + (lane & 31);
  f32x16 acc0 = {}, acc1 = {};

#pragma unroll
  for (int c = 0; c < 4; ++c) {
    if (wave < 8) {
      if (c < 2) {  // produce chunk c+2 into Pbuf[(c+2)%3]
        const int ts = (c + 2) * 8 + wave;
        float y[8][4];
        load_x(logits, b, ts * 16 + q * 8, j5, y);
        finish_ts(y, sm, n_lds, q_lds, Pbuf[(c + 2) % 3], wave,
                  ts * 16 + q * 8, lane, j5);
      } else if (c == 2) {  // all n/q atomics complete since end of c==1
        if (t < 128) slab_n[t * NB + b] = n_lds[t];
        else if (t < 256) slab_q[(t - 128) * NB + b] = q_lds[t - 128];
      }
    } else {  // GEMM chunk c
      const ushort* pl = Pbuf[c % 3] + (size_t)lane * 8;
#pragma unroll
      for (int tsl = 0; tsl < 8; ++tsl) {
        const int ks = c * 8 + tsl;
        const unsigned int w0 = sg4[ks * 4 + q * 2];
        const unsigned int w1 = sg4[ks * 4 + q * 2 + 1];
        U4V a;
        {
          const unsigned int s0 = w0 & 255u, s1 = (w0 >> 8) & 255u;
          const unsigned int s2 = (w0 >> 16) & 255u, s3 = w0 >> 24;
          const unsigned int s4 = w1 & 255u, s5 = (w1 >> 8) & 255u;
          const unsigned int s6 = (w1 >> 16) & 255u, s7 = w1 >> 24;
          const unsigned int um = (unsigned int)mm;
          a.u = make_uint4(
              (s0 == um ? 0x3F80u : 0u) | (s1 == um ? 0x3F800000u : 0u),
              (s2 == um ? 0x3F80u : 0u) | (s3 == um ? 0x3F800000u : 0u),
              (s4 == um ? 0x3F80u : 0u) | (s5 == um ? 0x3F800000u : 0u),
              (s6 == um ? 0x3F80u : 0u) | (s7 == um ? 0x3F800000u : 0u));
        }
        U4V b0, b1;
        b0.u = *(const uint4*)(pl + (size_t)(tsl * 4 + 2 * nh) * 512);
        b1.u = *(const uint4*)(pl + (size_t)(tsl * 4 + 2 * nh + 1) * 512);
        acc0 = __builtin_amdgcn_mfma_f32_32x32x16_bf16(a.v, b0.v, acc0,
                                                       0, 0, 0);
        acc1 = __builtin_amdgcn_mfma_f32_32x32x16_bf16(a.v, b1.v, acc1,
                                                       0, 0, 0);
      }
    }
    if (c < 3) __syncthreads();
  }

  if (wave >= 8) {
    // C/D layout (verified m74/m101 + rounds 7-9 absmax 0.0):
    // col = lane&31, row = (reg&3) + 8*(reg>>2) + 4*(lane>>5)
    float* outp = slab_s + (size_t)b * (CC * CC);
    const int jcol = lane & 31;
    const int rbase = (lane >> 5) * 4;
#pragma unroll
    for (int reg = 0; reg < 16; ++reg) {
      const int cr = m * 32 + (reg & 3) + 8 * (reg >> 2) + rbase;
      outp[cr * CC + (2 * nh) * 32 + jcol] = acc0[reg];
      outp[cr * CC + (2 * nh + 1) * 32 + jcol] = acc1[reg];
    }
  }
}

// ---------------- K3: reduce partials -> colvar -> atomic-merge -> out ------
// 128 blocks (one per column c) x 1024 thr. Unchanged from round 9.
__global__ __launch_bounds__(1024) void k3_colvar(
    const float* __restrict__ slab_s, const float* __restrict__ slab_n,
    const float* __restrict__ slab_q, float* __restrict__ acc,
    float* __restrict__ out) {
  const int c = blockIdx.x, t = threadIdx.x;
  const int v = t & 31, g0 = t >> 5;
  __shared__ float4 part[32][32];          // 16 KiB
  {
    const float4* base = (const float4*)slab_s +
                         (size_t)g0 * (CC * CC / 4) + c * (CC / 4) + v;
    float4 a = make_float4(0.f, 0.f, 0.f, 0.f);
#pragma unroll
    for (int i = 0; i < 8; ++i) {
      const float4 xx = base[(size_t)(32 * i) * (CC * CC / 4)];
      a.x += xx.x; a.y += xx.y; a.z += xx.z; a.w += xx.w;
    }
    part[g0][v] = a;
  }
  float np = 0.f, qp = 0.f;
  if (t >= 64 && t < 128) {                // wave 1: n row (256 floats)
    const int k = t - 64;
#pragma unroll
    for (int i = 0; i < 4; ++i) np += slab_n[c * NB + k + 64 * i];
  } else if (t >= 128 && t < 192) {        // wave 2: q row
    const int k = t - 128;
#pragma unroll
    for (int i = 0; i < 4; ++i) qp += slab_q[c * NB + k + 64 * i];
  }
  __syncthreads();
  float tp = 0.f;
  if (t < 32) {                            // wave 0: fold 32 g-groups, square
    float4 s = make_float4(0.f, 0.f, 0.f, 0.f);
#pragma unroll
    for (int g = 0; g < 32; ++g) {
      const float4 xx = part[g][v];
      s.x += xx.x; s.y += xx.y; s.z += xx.z; s.w += xx.w;
    }
    tp = s.x * s.x + s.y * s.y + s.z * s.z + s.w * s.w;
  }
#pragma unroll
  for (int off = 1; off < 64; off <<= 1) { // wave0: tp; wave1: np; wave2: qp
    tp += __shfl_xor(tp, off, 64);
    np += __shfl_xor(np, off, 64);
    qp += __shfl_xor(qp, off, 64);
  }
  __shared__ float fin[3];
  if (t == 0) fin[0] = tp;
  else if (t == 64) fin[1] = np;
  else if (t == 128) fin[2] = qp;
  __syncthreads();
  if (t == 0) {
    const float tt = fin[0], nn = fin[1], qq = fin[2];
    float cv = 0.f, fl = 0.f;
    if (nn > 1.0f) {
      cv = (qq - tt / nn) / (nn * (float)CC);
      fl = 1.f;
    }
    atomicAdd(&acc[0], cv);
    atomicAdd(&acc[1], fl);
    __threadfence();
    const unsigned int old = atomicAdd((unsigned int*)&acc[2], 1u);
    if (old == (unsigned int)(CC - 1)) {   // last block: finalize
      const float total = atomicAdd(&acc[0], 0.f);
      const float count = atomicAdd(&acc[1], 0.f);
      out[0] = (count > 0.f) ? total / fmaxf(count, 1.f) : 0.f;
    }
  }
}

// =================== launch =================================================
extern "C" void kernel_launch(void* const* d_in, const int* in_sizes, int n_in,
                              void* d_out, int out_size, void* d_ws,
                              size_t ws_size, hipStream_t stream) {
  const float* logits = (const float*)d_in[0];
  const int* seg = (const int*)d_in[1];
  const int* mask = (const int*)d_in[2];
  float* out = (float*)d_out;

  // ws layout (16.8 MB; harness provides ~268 MB):
  // slab_s f32[256][128][128] | slab_n f32[128][256] | slab_q f32[128][256] |
  // acc f32[4] (total, count, done-ticket, pad) — zeroed by fused block 0.
  float* slab_s = (float*)d_ws;
  float* slab_n = slab_s + (size_t)NB * CC * CC;
  float* slab_q = slab_n + CC * NB;
  float* acc = slab_q + CC * NB;
  fused_kernel<<<NB, 1024, 0, stream>>>(logits, seg, mask, slab_s, slab_n,
                                        slab_q, acc);
  k3_colvar<<<CC, 1024, 0, stream>>>(slab_s, slab_n, slab_q, acc, out);
}

// Round 3
// 110.768 us; speedup vs baseline: 1.0059x; 1.0059x over previous
//
#include <hip/hip_runtime.h>
#include <hip/hip_bf16.h>

// ColumnConsistencyLoss: B=16, T=8192, C=128.
// out = mean over columns c with n_c>1 of (q_c - t_c/n_c)/(n_c*C)
//   n_c = # valid rows with seg=c ; q_c = sum z2/z^2 over those rows
//   s[c][j] = sum p_j over those rows ; t_c = sum_j s[c][j]^2
//
// Round-11: revert round-10's producer/consumer split (regressed +1.7 us:
// halving load-issuing waves hurt — phase 1 is load-concurrency-bound).
// Back to round-9 structure (16 waves produce all 32 ksteps, 4-wave GEMM
// tail), with two targeted changes:
//  - Phase-1 logits loads float4-vectorized (32 global_load_dword ->
//    8 dwordx4 per thread per kstep; one base + imm offsets). Lane now owns
//    4 CONSECUTIVE columns; the bf16 B-frag pack therefore writes at
//    n*16-byte stride which would collapse 64 lanes onto 8 banks -> XOR
//    swizzle addr ^= ((n>>3)&3)<<4 on BOTH pack-write and GEMM-read sides
//    (derivation: write banks 8 distinct 4-bank spans = ideal 8cy; read
//    spread even). Fragment CONTENTS identical to round 9 (absmax 0.0).
//  - 32-lane reduce via 4x DPP row_ror + 1 ds_swizzle xor16 (hw-verified
//    round 10, absmax 0.0) instead of 10 ds-shuffle ops per row.
// ~85-90 us of dur_us is harness ws-poison (268 MB fill @ 6.5 TB/s) +
// d_in restore — not addressable from kernel code.

#define NROWS 131072
#define CC    128
#define NB    256
#define RPB   512   // rows per block

typedef float f32x16 __attribute__((ext_vector_type(16)));
typedef short bf16x8 __attribute__((ext_vector_type(8)));

union U4V { uint4 u; bf16x8 v; };
union H2U { __hip_bfloat162 h; unsigned int u; };

// Sum over 32 consecutive lanes: 4x DPP row_ror (VALU pipe, rows of 16)
// + 1 ds_swizzle xor16 to combine the two 16-rows. All lanes get the sum.
// Hardware-verified (round 10, absmax 0.0).
__device__ __forceinline__ float red32(float x) {
  x += __int_as_float(__builtin_amdgcn_update_dpp(
      0, __float_as_int(x), 0x121, 0xF, 0xF, true));  // row_ror:1
  x += __int_as_float(__builtin_amdgcn_update_dpp(
      0, __float_as_int(x), 0x122, 0xF, 0xF, true));  // row_ror:2
  x += __int_as_float(__builtin_amdgcn_update_dpp(
      0, __float_as_int(x), 0x124, 0xF, 0xF, true));  // row_ror:4
  x += __int_as_float(__builtin_amdgcn_update_dpp(
      0, __float_as_int(x), 0x128, 0xF, 0xF, true));  // row_ror:8
  x += __int_as_float(
      __builtin_amdgcn_ds_swizzle(__float_as_int(x), 0x401F));  // xor 16
  return x;
}

// ---------------- Fused: softmax -> LDS P -> one-hot MFMA -> partial slab ---
// 256 blocks x 1024 thr (16 waves). LDS ~131.5 KiB -> 1 block/CU.
// Phase 1 (all 16 waves): wave handles 32 rows = ksteps 2w,2w+1.
//   lane = 32q + j5; half q owns rows rb..rb+7; lane j5 owns cols
//   4j5..4j5+3 (float4 load). Pack target slot (ts,nt,q,n):
//   byte = (ts*4+nt)*1024 + ((q*512 + n*16) ^ ((n>>3&3)<<4)).
// Phase 2 (waves 0-3): wave = m-tile (32 c's), 32 ksteps, 4 n-tiles,
//   b-frags via swizzled ds_read_b128 (per-lane-constant offset).
__global__ __launch_bounds__(1024) void fused_kernel(
    const float* __restrict__ logits, const int* __restrict__ seg,
    const int* __restrict__ mask, float* __restrict__ slab_s,
    float* __restrict__ slab_n, float* __restrict__ slab_q,
    float* __restrict__ acc) {
  __shared__ ushort Plds[RPB * CC];        // 128 KiB
  __shared__ int sm[RPB];                  // 2 KiB: seg | mask<<16
  __shared__ unsigned int sg4[128];        // packed seg-bytes (255=invalid)
  __shared__ float n_lds[CC], q_lds[CC];   // 1 KiB
  const int t = threadIdx.x, b = blockIdx.x;
  if (b == 0 && t < 4) ((unsigned int*)acc)[t] = 0u;  // (total,count,ticket)
  if (t < CC) { n_lds[t] = 0.f; q_lds[t] = 0.f; }
  if (t < RPB) {
    const int r = b * RPB + t;
    sm[t] = seg[r] | (mask[r] << 16);
  }
  __syncthreads();
  if (t < 128) {
    unsigned int w = 0;
#pragma unroll
    for (int k = 0; k < 4; ++k) {
      const int smv = sm[t * 4 + k];
      const unsigned int sv = (smv >> 16) ? (unsigned int)(smv & 0xFFFF) : 255u;
      w |= sv << (8 * k);
    }
    sg4[t] = w;
  }

  const int wave = t >> 6, lane = t & 63;
  const int q = lane >> 5, j5 = lane & 31;
  // Per-lane constant pack-write geometry (see header comment):
  // base byte = (ts*4 + (j5>>3))*1024 + q*512 + (j5&7)*64 + (m*16 ^ swz)
  const int swz = ((j5 >> 1) & 3) << 4;
  char* const pb0 = (char*)Plds + q * 512 + (j5 & 7) * 64;

#pragma unroll
  for (int g = 0; g < 2; ++g) {
    const int ts = 2 * wave + g;           // kstep in [0,32)
    const int rb = ts * 16 + q * 8;        // local row base (+i)
    const float4* rp4 =
        (const float4*)(logits + (size_t)(b * RPB + rb) * CC) + j5;
    float x[8][4];
#pragma unroll
    for (int i = 0; i < 8; ++i) {
      const float4 v = rp4[i * 32];        // row rb+i, cols 4j5..4j5+3
      x[i][0] = v.x; x[i][1] = v.y; x[i][2] = v.z; x[i][3] = v.w;
    }
    float inv[8], qr[8];
#pragma unroll
    for (int i = 0; i < 8; ++i) {
      float z = 0.f, z2 = 0.f;
#pragma unroll
      for (int m = 0; m < 4; ++m) {
        const float e = __expf(x[i][m]);
        x[i][m] = e; z += e; z2 += e * e;
      }
      z = red32(z);
      z2 = red32(z2);
      inv[i] = 1.0f / z;
      qr[i] = z2 * inv[i] * inv[i];
    }
    char* const pbt = pb0 + (size_t)(ts * 4 + (j5 >> 3)) * 1024;
#pragma unroll
    for (int m = 0; m < 4; ++m) {          // column 4*j5 + m
      unsigned int d[4];
#pragma unroll
      for (int k = 0; k < 4; ++k) {
        H2U h;
        h.h = __float22bfloat162_rn(make_float2(
            x[2 * k][m] * inv[2 * k], x[2 * k + 1][m] * inv[2 * k + 1]));
        d[k] = h.u;
      }
      *(uint4*)(pbt + ((m * 16) ^ swz)) = make_uint4(d[0], d[1], d[2], d[3]);
    }
    if (j5 == 0) {
#pragma unroll
      for (int i = 0; i < 8; ++i) {
        const int smv = sm[rb + i];
        if (smv >> 16) {
          atomicAdd(&n_lds[smv & 0xFFFF], 1.0f);
          atomicAdd(&q_lds[smv & 0xFFFF], qr[i]);
        }
      }
    }
  }
  __syncthreads();

  // n/q slab write by waves 4-7 (GEMM waves start immediately).
  if (t >= 256 && t < 384) slab_n[(t - 256) * NB + b] = n_lds[t - 256];
  else if (t >= 384 && t < 512) slab_q[(t - 384) * NB + b] = q_lds[t - 384];

  if (wave < 4) {
    const int mm = wave * 32 + (lane & 31);
    f32x16 acc0 = {}, acc1 = {}, acc2 = {}, acc3 = {};
    // Per-lane constant swizzled read offset: slot (*,nt,q,n=lane&31).
    const int nrd = lane & 31;
    const char* pl = (char*)Plds +
        ((q * 512 + nrd * 16) ^ (((nrd >> 3) & 3) << 4));
    for (int ks = 0; ks < 32; ++ks) {
      const unsigned int w0 = sg4[ks * 4 + q * 2];
      const unsigned int w1 = sg4[ks * 4 + q * 2 + 1];
      U4V a;
      {
        const unsigned int s0 = w0 & 255u, s1 = (w0 >> 8) & 255u;
        const unsigned int s2 = (w0 >> 16) & 255u, s3 = w0 >> 24;
        const unsigned int s4 = w1 & 255u, s5 = (w1 >> 8) & 255u;
        const unsigned int s6 = (w1 >> 16) & 255u, s7 = w1 >> 24;
        const unsigned int um = (unsigned int)mm;
        a.u = make_uint4(
            (s0 == um ? 0x3F80u : 0u) | (s1 == um ? 0x3F800000u : 0u),
            (s2 == um ? 0x3F80u : 0u) | (s3 == um ? 0x3F800000u : 0u),
            (s4 == um ? 0x3F80u : 0u) | (s5 == um ? 0x3F800000u : 0u),
            (s6 == um ? 0x3F80u : 0u) | (s7 == um ? 0x3F800000u : 0u));
      }
      U4V b0, b1, b2, b3;
      b0.u = *(const uint4*)(pl + (size_t)(ks * 4 + 0) * 1024);
      b1.u = *(const uint4*)(pl + (size_t)(ks * 4 + 1) * 1024);
      b2.u = *(const uint4*)(pl + (size_t)(ks * 4 + 2) * 1024);
      b3.u = *(const uint4*)(pl + (size_t)(ks * 4 + 3) * 1024);
      acc0 = __builtin_amdgcn_mfma_f32_32x32x16_bf16(a.v, b0.v, acc0, 0, 0, 0);
      acc1 = __builtin_amdgcn_mfma_f32_32x32x16_bf16(a.v, b1.v, acc1, 0, 0, 0);
      acc2 = __builtin_amdgcn_mfma_f32_32x32x16_bf16(a.v, b2.v, acc2, 0, 0, 0);
      acc3 = __builtin_amdgcn_mfma_f32_32x32x16_bf16(a.v, b3.v, acc3, 0, 0, 0);
    }
    // C/D layout (verified m74/m101 + rounds 7-10 absmax 0.0):
    // col = lane&31, row = (reg&3) + 8*(reg>>2) + 4*(lane>>5)
    float* outp = slab_s + (size_t)b * (CC * CC);
    const int jcol = lane & 31;
    const int rbase = (lane >> 5) * 4;
#pragma unroll
    for (int reg = 0; reg < 16; ++reg) {
      const int c = wave * 32 + (reg & 3) + 8 * (reg >> 2) + rbase;
      outp[c * CC + 0 * 32 + jcol] = acc0[reg];
      outp[c * CC + 1 * 32 + jcol] = acc1[reg];
      outp[c * CC + 2 * 32 + jcol] = acc2[reg];
      outp[c * CC + 3 * 32 + jcol] = acc3[reg];
    }
  }
}

// ---------------- K3: reduce partials -> colvar -> atomic-merge -> out ------
// 128 blocks (one per column c) x 1024 thr. Unchanged from round 9.
__global__ __launch_bounds__(1024) void k3_colvar(
    const float* __restrict__ slab_s, const float* __restrict__ slab_n,
    const float* __restrict__ slab_q, float* __restrict__ acc,
    float* __restrict__ out) {
  const int c = blockIdx.x, t = threadIdx.x;
  const int v = t & 31, g0 = t >> 5;
  __shared__ float4 part[32][32];          // 16 KiB
  {
    const float4* base = (const float4*)slab_s +
                         (size_t)g0 * (CC * CC / 4) + c * (CC / 4) + v;
    float4 a = make_float4(0.f, 0.f, 0.f, 0.f);
#pragma unroll
    for (int i = 0; i < 8; ++i) {
      const float4 xx = base[(size_t)(32 * i) * (CC * CC / 4)];
      a.x += xx.x; a.y += xx.y; a.z += xx.z; a.w += xx.w;
    }
    part[g0][v] = a;
  }
  float np = 0.f, qp = 0.f;
  if (t >= 64 && t < 128) {                // wave 1: n row (256 floats)
    const int k = t - 64;
#pragma unroll
    for (int i = 0; i < 4; ++i) np += slab_n[c * NB + k + 64 * i];
  } else if (t >= 128 && t < 192) {        // wave 2: q row
    const int k = t - 128;
#pragma unroll
    for (int i = 0; i < 4; ++i) qp += slab_q[c * NB + k + 64 * i];
  }
  __syncthreads();
  float tp = 0.f;
  if (t < 32) {                            // wave 0: fold 32 g-groups, square
    float4 s = make_float4(0.f, 0.f, 0.f, 0.f);
#pragma unroll
    for (int g = 0; g < 32; ++g) {
      const float4 xx = part[g][v];
      s.x += xx.x; s.y += xx.y; s.z += xx.z; s.w += xx.w;
    }
    tp = s.x * s.x + s.y * s.y + s.z * s.z + s.w * s.w;
  }
#pragma unroll
  for (int off = 1; off < 64; off <<= 1) { // wave0: tp; wave1: np; wave2: qp
    tp += __shfl_xor(tp, off, 64);
    np += __shfl_xor(np, off, 64);
    qp += __shfl_xor(qp, off, 64);
  }
  __shared__ float fin[3];
  if (t == 0) fin[0] = tp;
  else if (t == 64) fin[1] = np;
  else if (t == 128) fin[2] = qp;
  __syncthreads();
  if (t == 0) {
    const float tt = fin[0], nn = fin[1], qq = fin[2];
    float cv = 0.f, fl = 0.f;
    if (nn > 1.0f) {
      cv = (qq - tt / nn) / (nn * (float)CC);
      fl = 1.f;
    }
    atomicAdd(&acc[0], cv);
    atomicAdd(&acc[1], fl);
    __threadfence();
    const unsigned int old = atomicAdd((unsigned int*)&acc[2], 1u);
    if (old == (unsigned int)(CC - 1)) {   // last block: finalize
      const float total = atomicAdd(&acc[0], 0.f);
      const float count = atomicAdd(&acc[1], 0.f);
      out[0] = (count > 0.f) ? total / fmaxf(count, 1.f) : 0.f;
    }
  }
}

// =================== launch =================================================
extern "C" void kernel_launch(void* const* d_in, const int* in_sizes, int n_in,
                              void* d_out, int out_size, void* d_ws,
                              size_t ws_size, hipStream_t stream) {
  const float* logits = (const float*)d_in[0];
  const int* seg = (const int*)d_in[1];
  const int* mask = (const int*)d_in[2];
  float* out = (float*)d_out;

  // ws layout (16.8 MB; harness provides ~268 MB):
  // slab_s f32[256][128][128] | slab_n f32[128][256] | slab_q f32[128][256] |
  // acc f32[4] (total, count, done-ticket, pad) — zeroed by fused block 0.
  float* slab_s = (float*)d_ws;
  float* slab_n = slab_s + (size_t)NB * CC * CC;
  float* slab_q = slab_n + CC * NB;
  float* acc = slab_q + CC * NB;
  fused_kernel<<<NB, 1024, 0, stream>>>(logits, seg, mask, slab_s, slab_n,
                                        slab_q, acc);
  k3_colvar<<<CC, 1024, 0, stream>>>(slab_s, slab_n, slab_q, acc, out);
}